// Round 8
// baseline (38.841 us; speedup 1.0000x reference)
//
#include <hip/hip_runtime.h>
#include <hip/hip_bf16.h>

// (B,L,H,E,D) = (2,2048,8,64,64); E==D==64.
namespace {
constexpr int Lc = 2048, Hc = 8;
constexpr int RS = Hc * 64;          // floats between consecutive l (=512)
constexpr int NKT = 32;              // 2048/64 kt tiles
constexpr int TILE_BYTES = 16384;    // K frags 8KB + V frags 8KB per (bh,kt)
}

typedef __attribute__((ext_vector_type(8))) short bf16x8;
typedef __attribute__((ext_vector_type(16))) float f32x16;
typedef unsigned int u32;
typedef __attribute__((ext_vector_type(4))) u32 u32x4;

__device__ __forceinline__ u32 bfu(float x) {
    return (u32)__builtin_bit_cast(unsigned short, __float2bfloat16(x));
}
__device__ __forceinline__ short f2bf(float x) {
    return (short)__builtin_bit_cast(unsigned short, __float2bfloat16(x));
}

#define MFMA32(a, b, c) __builtin_amdgcn_mfma_f32_32x32x16_bf16((a), (b), (c), 0, 0, 0)

#define GLL16(gp, lp) __builtin_amdgcn_global_load_lds( \
    (const __attribute__((address_space(1))) unsigned int*)(gp), \
    (__attribute__((address_space(3))) unsigned int*)(lp), 16, 0, 0)

// ------------- prep: f32 K,V -> bf16 32x32x16-fragment-ordered tiles in ws -------------
// (unchanged from round 7 — validated)
__global__ __launch_bounds__(256)
void prep_kv(const float* __restrict__ kg, const float* __restrict__ vg,
             short* __restrict__ ws)
{
    const int kt = blockIdx.x, bh = blockIdx.y;
    const int b = bh >> 3, h = bh & 7;
    const size_t base = ((size_t)b * Lc * Hc + h) * 64;
    char* tile = (char*)ws + (size_t)(bh * NKT + kt) * TILE_BYTES;
    const int tid = threadIdx.x;

    {   // K A-frags
        const int c = tid & 7, e0 = c * 8;
        #pragma unroll
        for (int p = 0; p < 2; ++p) {
            const int s = (tid >> 3) + 32 * p;
            const float* src = kg + base + (size_t)(kt * 64 + s) * RS + e0;
            float4 x0 = *(const float4*)src;
            float4 x1 = *(const float4*)(src + 4);
            bf16x8 w = { f2bf(x0.x), f2bf(x0.y), f2bf(x0.z), f2bf(x0.w),
                         f2bf(x1.x), f2bf(x1.y), f2bf(x1.z), f2bf(x1.w) };
            const int lane = (c & 1) * 32 + (s & 31);
            const int byte = ((s >> 5) * 4 + (c >> 1)) * 1024 + lane * 16;
            *(bf16x8*)(tile + byte) = w;
        }
    }
    {   // V B-frags
        const int d = tid & 63;
        #pragma unroll
        for (int p = 0; p < 2; ++p) {
            const int sblk = (tid >> 6) + 4 * p;
            const int s0 = sblk * 8;
            float xv[8];
            #pragma unroll
            for (int j = 0; j < 8; ++j)
                xv[j] = vg[base + (size_t)(kt * 64 + s0 + j) * RS + d];
            bf16x8 w = { f2bf(xv[0]), f2bf(xv[1]), f2bf(xv[2]), f2bf(xv[3]),
                         f2bf(xv[4]), f2bf(xv[5]), f2bf(xv[6]), f2bf(xv[7]) };
            const int lane = (sblk & 1) * 32 + (d & 31);
            const int byte = 8192 + ((d >> 5) * 4 + (sblk >> 1)) * 1024 + lane * 16;
            *(bf16x8*)(tile + byte) = w;
        }
    }
}

// ------- attention: sequential strips {31-pr, pr}, 8 waves = qs(2) x ktp(4) -------
__global__ __launch_bounds__(512, 1)
void gate_attn(const float* __restrict__ ug, const float* __restrict__ qg,
               const short* __restrict__ ws, float* __restrict__ outg)
{
    __shared__ __align__(16) char lds[2][4 * TILE_BYTES];   // 128KB: dbuf x 4-tile group

    const int tid = threadIdx.x;
    const int wave = tid >> 6, lane = tid & 63;
    const int col = lane & 31, hi = lane >> 5;
    const int qs = wave & 1, ktp = wave >> 1;     // q sub-block / kt mod-4 class

    const int pr = blockIdx.x, bh = blockIdx.y;
    const int b = bh >> 3, h = bh & 7;
    const size_t base = ((size_t)b * Lc * Hc + h) * 64;
    const char* wsbh = (const char*)ws + (size_t)bh * NKT * TILE_BYTES;

    auto STAGEG = [&](int t0, int buf) {          // stage tiles t0..t0+3 (64KB)
        const char* src = wsbh + (size_t)t0 * TILE_BYTES + tid * 16;
        char* dst = &lds[buf][0] + tid * 16;
        #pragma unroll
        for (int i = 0; i < 8; ++i)
            GLL16(src + i * 8192, dst + i * 8192);
    };

    auto RUN_STRIP = [&](int strip) {
        const int NTs = strip + 1;
        const int IT = (NTs + 3) >> 2;
        const int qw = strip * 64 + qs * 32;
        const int qg_l = qw + col;

        // Q B-fragments for this strip
        bf16x8 qf[4];
        #pragma unroll
        for (int es = 0; es < 4; ++es) {
            const float* p = qg + base + (size_t)(qw + col) * RS + es * 16 + hi * 8;
            float4 a = *(const float4*)p;
            float4 c2 = *(const float4*)(p + 4);
            qf[es] = (bf16x8){ f2bf(a.x),  f2bf(a.y),  f2bf(a.z),  f2bf(a.w),
                               f2bf(c2.x), f2bf(c2.y), f2bf(c2.z), f2bf(c2.w) };
        }

        f32x16 oacc[2];
        #pragma unroll
        for (int r = 0; r < 16; ++r) { oacc[0][r] = 0.f; oacc[1][r] = 0.f; }

        STAGEG(0, 0);
        __syncthreads();

        for (int it = 0; it < IT; ++it) {
            if (it + 1 < IT) STAGEG(4 * (it + 1), (it & 1) ^ 1);
            const int kt = 4 * it + ktp;
            if (kt <= strip) {
                const char* kb = &lds[it & 1][0] + ktp * TILE_BYTES;

                // ---- swapped QK^T (validated r7 path) ----
                f32x16 sacc[2];
                #pragma unroll
                for (int r = 0; r < 16; ++r) { sacc[0][r] = 0.f; sacc[1][r] = 0.f; }
                #pragma unroll
                for (int sb = 0; sb < 2; ++sb)
                    #pragma unroll
                    for (int es = 0; es < 4; ++es) {
                        bf16x8 kf = *(const bf16x8*)(kb + (sb * 4 + es) * 1024 + lane * 16);
                        sacc[sb] = MFMA32(kf, qf[es], sacc[sb]);
                    }

                // ---- relu^2 + mask; pack; permlane -> PA frags ----
                const bool dmask = (kt == strip);
                u32 pa[4][4];
                #pragma unroll
                for (int sb = 0; sb < 2; ++sb) {
                    float pv[16];
                    #pragma unroll
                    for (int r = 0; r < 16; ++r) {
                        float x = sacc[sb][r];
                        x = (x > 0.f) ? x * x : 0.f;
                        const int s_g = kt * 64 + sb * 32 + (r & 3) + 8 * (r >> 2) + 4 * hi;
                        if (dmask && s_g > qg_l) x = 0.f;
                        pv[r] = x;
                    }
                    u32 W[8];
                    #pragma unroll
                    for (int t = 0; t < 8; ++t)
                        W[t] = bfu(pv[2 * t]) | (bfu(pv[2 * t + 1]) << 16);
                    asm volatile("v_permlane32_swap_b32 %0, %1" : "+v"(W[0]), "+v"(W[2]));
                    asm volatile("v_permlane32_swap_b32 %0, %1" : "+v"(W[1]), "+v"(W[3]));
                    asm volatile("v_permlane32_swap_b32 %0, %1" : "+v"(W[4]), "+v"(W[6]));
                    asm volatile("v_permlane32_swap_b32 %0, %1" : "+v"(W[5]), "+v"(W[7]));
                    pa[sb * 2 + 0][0] = W[0]; pa[sb * 2 + 0][1] = W[1];
                    pa[sb * 2 + 0][2] = W[2]; pa[sb * 2 + 0][3] = W[3];
                    pa[sb * 2 + 1][0] = W[4]; pa[sb * 2 + 1][1] = W[5];
                    pa[sb * 2 + 1][2] = W[6]; pa[sb * 2 + 1][3] = W[7];
                }

                // ---- PV ----
                const char* vb = kb + 8192;
                #pragma unroll
                for (int dh = 0; dh < 2; ++dh)
                    #pragma unroll
                    for (int ks = 0; ks < 4; ++ks) {
                        bf16x8 vf = *(const bf16x8*)(vb + (dh * 4 + ks) * 1024 + lane * 16);
                        u32x4 pw = { pa[ks][0], pa[ks][1], pa[ks][2], pa[ks][3] };
                        oacc[dh] = MFMA32(__builtin_bit_cast(bf16x8, pw), vf, oacc[dh]);
                    }
            }
            __syncthreads();
        }

        // ---- 4-way ktp reduction through LDS + fused u-gate epilogue ----
        float* red = (float*)&lds[0][0];   // [ktp][qs][m(32)][d(64)] = 64KB
        #pragma unroll
        for (int dh = 0; dh < 2; ++dh)
            #pragma unroll
            for (int r = 0; r < 16; ++r) {
                const int m = (r & 3) + 8 * (r >> 2) + 4 * hi;
                red[(((ktp * 2 + qs) * 32) + m) * 64 + dh * 32 + col] = oacc[dh][r];
            }
        __syncthreads();

        const float sc = 1.0f / (64.0f * 2048.0f);   // exact pow2
        #pragma unroll
        for (int rr = 0; rr < 2; ++rr) {
            const int e4 = rr * 512 + tid;           // 0..1023 float4 outputs
            const int row = e4 >> 4, d4 = (e4 & 15) * 4;
            const int rqs = row >> 5, m = row & 31;
            float4 s = make_float4(0.f, 0.f, 0.f, 0.f);
            #pragma unroll
            for (int k = 0; k < 4; ++k) {
                const float4 p = *(const float4*)&red[(((k * 2 + rqs) * 32) + m) * 64 + d4];
                s.x += p.x; s.y += p.y; s.z += p.z; s.w += p.w;
            }
            const size_t idx = base + (size_t)(strip * 64 + row) * RS + d4;
            const float4 uu = *(const float4*)&ug[idx];
            float4 o;
            o.x = uu.x * s.x * sc; o.y = uu.y * s.y * sc;
            o.z = uu.z * s.z * sc; o.w = uu.w * s.w * sc;
            *(float4*)&outg[idx] = o;
        }
        __syncthreads();   // red / staging buffers free for next phase
    };

    RUN_STRIP(31 - pr);    // heavy strip: all 8 waves
    RUN_STRIP(pr);         // light strip: all 8 waves
}

extern "C" void kernel_launch(void* const* d_in, const int* in_sizes, int n_in,
                              void* d_out, int out_size, void* d_ws, size_t ws_size,
                              hipStream_t stream) {
    const float* u = (const float*)d_in[0];
    const float* q = (const float*)d_in[1];
    const float* k = (const float*)d_in[2];
    const float* v = (const float*)d_in[3];
    // d_in[4] (mask) is strict-upper-triangular; implemented analytically.
    float* out = (float*)d_out;

    // ws: 16 bh x 32 kt x 16KB = 8 MiB fragment-ordered bf16 K/V tiles
    prep_kv<<<dim3(NKT, 16), dim3(256), 0, stream>>>(k, v, (short*)d_ws);
    gate_attn<<<dim3(16, 16), dim3(512), 0, stream>>>(u, q, (const short*)d_ws, out);
}

// Round 9
// 36.034 us; speedup vs baseline: 1.0779x; 1.0779x over previous
//
#include <hip/hip_runtime.h>
#include <hip/hip_bf16.h>

// (B,L,H,E,D) = (2,2048,8,64,64); E==D==64.
namespace {
constexpr int Lc = 2048, Hc = 8;
constexpr int RS = Hc * 64;          // floats between consecutive l (=512)
constexpr int NKT = 32;              // 2048/64 kt tiles
constexpr int TILE_BYTES = 16384;    // K frags 8KB + V frags 8KB per (bh,kt)
}

typedef __attribute__((ext_vector_type(8))) short bf16x8;
typedef __attribute__((ext_vector_type(16))) float f32x16;
typedef unsigned int u32;
typedef __attribute__((ext_vector_type(4))) u32 u32x4;

__device__ __forceinline__ u32 bfu(float x) {
    return (u32)__builtin_bit_cast(unsigned short, __float2bfloat16(x));
}
__device__ __forceinline__ short f2bf(float x) {
    return (short)__builtin_bit_cast(unsigned short, __float2bfloat16(x));
}

#define MFMA32(a, b, c) __builtin_amdgcn_mfma_f32_32x32x16_bf16((a), (b), (c), 0, 0, 0)

#define GLL16(gp, lp) __builtin_amdgcn_global_load_lds( \
    (const __attribute__((address_space(1))) unsigned int*)(gp), \
    (__attribute__((address_space(3))) unsigned int*)(lp), 16, 0, 0)

// ------------- prep: f32 K,V -> bf16 32x32x16-fragment-ordered tiles in ws -------------
// (unchanged — validated rounds 7-8)
__global__ __launch_bounds__(256)
void prep_kv(const float* __restrict__ kg, const float* __restrict__ vg,
             short* __restrict__ ws)
{
    const int kt = blockIdx.x, bh = blockIdx.y;
    const int b = bh >> 3, h = bh & 7;
    const size_t base = ((size_t)b * Lc * Hc + h) * 64;
    char* tile = (char*)ws + (size_t)(bh * NKT + kt) * TILE_BYTES;
    const int tid = threadIdx.x;

    {   // K A-frags
        const int c = tid & 7, e0 = c * 8;
        #pragma unroll
        for (int p = 0; p < 2; ++p) {
            const int s = (tid >> 3) + 32 * p;
            const float* src = kg + base + (size_t)(kt * 64 + s) * RS + e0;
            float4 x0 = *(const float4*)src;
            float4 x1 = *(const float4*)(src + 4);
            bf16x8 w = { f2bf(x0.x), f2bf(x0.y), f2bf(x0.z), f2bf(x0.w),
                         f2bf(x1.x), f2bf(x1.y), f2bf(x1.z), f2bf(x1.w) };
            const int lane = (c & 1) * 32 + (s & 31);
            const int byte = ((s >> 5) * 4 + (c >> 1)) * 1024 + lane * 16;
            *(bf16x8*)(tile + byte) = w;
        }
    }
    {   // V B-frags
        const int d = tid & 63;
        #pragma unroll
        for (int p = 0; p < 2; ++p) {
            const int sblk = (tid >> 6) + 4 * p;
            const int s0 = sblk * 8;
            float xv[8];
            #pragma unroll
            for (int j = 0; j < 8; ++j)
                xv[j] = vg[base + (size_t)(kt * 64 + s0 + j) * RS + d];
            bf16x8 w = { f2bf(xv[0]), f2bf(xv[1]), f2bf(xv[2]), f2bf(xv[3]),
                         f2bf(xv[4]), f2bf(xv[5]), f2bf(xv[6]), f2bf(xv[7]) };
            const int lane = (sblk & 1) * 32 + (d & 31);
            const int byte = 8192 + ((d >> 5) * 4 + (sblk >> 1)) * 1024 + lane * 16;
            *(bf16x8*)(tile + byte) = w;
        }
    }
}

// ---- attention: 256 thr (4 waves = qs x ktp), one strip/block, 2 blocks/CU ----
__global__ __launch_bounds__(256, 2)
void gate_attn(const float* __restrict__ ug, const float* __restrict__ qg,
               const short* __restrict__ ws, float* __restrict__ outg)
{
    __shared__ __align__(16) char lds[2][2 * TILE_BYTES];   // 64KB: dbuf x 2-tile group

    const int tid = threadIdx.x;
    const int wave = tid >> 6, lane = tid & 63;
    const int col = lane & 31, hi = lane >> 5;
    const int qs = wave & 1, ktp = wave >> 1;    // q sub-block / kt parity

    // XCD-local bh + complementary strip pairing:
    //   xcd = i&7 owns bh {2*xcd, 2*xcd+1} (ws footprint 1MB -> L2-resident);
    //   round r=0 (w<32): strip 31-x (heavy), round r=1: strip x (light)
    //   -> round-robin CU pairing gives uniform 17 iterations/CU.
    const int i = (int)blockIdx.x;
    const int xcd = i & 7, w = i >> 3;
    const int bh = 2 * xcd + (w >= 32 ? 1 : 0);
    const int x = w & 31;
    const int strip = (w < 32) ? (31 - x) : x;

    const int b = bh >> 3, h = bh & 7;
    const size_t base = ((size_t)b * Lc * Hc + h) * 64;
    const char* wsbh = (const char*)ws + (size_t)bh * NKT * TILE_BYTES;

    const int IT = ((strip + 1) + 1) >> 1;       // kt-pair iterations
    const int qw = strip * 64 + qs * 32;
    const int qg_l = qw + col;

    // ---- Q B-fragments ----
    bf16x8 qf[4];
    #pragma unroll
    for (int es = 0; es < 4; ++es) {
        const float* p = qg + base + (size_t)(qw + col) * RS + es * 16 + hi * 8;
        float4 a = *(const float4*)p;
        float4 c2 = *(const float4*)(p + 4);
        qf[es] = (bf16x8){ f2bf(a.x),  f2bf(a.y),  f2bf(a.z),  f2bf(a.w),
                           f2bf(c2.x), f2bf(c2.y), f2bf(c2.z), f2bf(c2.w) };
    }

    auto STAGEG = [&](int t0, int buf) {         // stage tiles t0, t0+1 (32KB)
        #pragma unroll
        for (int t = 0; t < 2; ++t) {
            if (t0 + t <= strip) {
                const char* src = wsbh + (size_t)(t0 + t) * TILE_BYTES + tid * 16;
                char* dst = &lds[buf][t * TILE_BYTES] + tid * 16;
                #pragma unroll
                for (int j = 0; j < 4; ++j)
                    GLL16(src + j * 4096, dst + j * 4096);
            }
        }
    };

    f32x16 oacc[2];
    #pragma unroll
    for (int r = 0; r < 16; ++r) { oacc[0][r] = 0.f; oacc[1][r] = 0.f; }

    STAGEG(0, 0);
    __syncthreads();

    for (int it = 0; it < IT; ++it) {
        if (it + 1 < IT) STAGEG(2 * (it + 1), (it & 1) ^ 1);
        const int kt = 2 * it + ktp;
        if (kt <= strip) {
            const char* kb = &lds[it & 1][ktp * TILE_BYTES];

            // ---- swapped QK^T (validated r7 path) ----
            f32x16 sacc[2];
            #pragma unroll
            for (int r = 0; r < 16; ++r) { sacc[0][r] = 0.f; sacc[1][r] = 0.f; }
            __builtin_amdgcn_s_setprio(1);
            #pragma unroll
            for (int sb = 0; sb < 2; ++sb)
                #pragma unroll
                for (int es = 0; es < 4; ++es) {
                    bf16x8 kf = *(const bf16x8*)(kb + (sb * 4 + es) * 1024 + lane * 16);
                    sacc[sb] = MFMA32(kf, qf[es], sacc[sb]);
                }
            __builtin_amdgcn_s_setprio(0);

            // ---- relu^2 + mask; pack; permlane -> PA frags ----
            const bool dmask = (kt == strip);
            u32 pa[4][4];
            #pragma unroll
            for (int sb = 0; sb < 2; ++sb) {
                float pv[16];
                #pragma unroll
                for (int r = 0; r < 16; ++r) {
                    float x2 = sacc[sb][r];
                    x2 = (x2 > 0.f) ? x2 * x2 : 0.f;
                    const int s_g = kt * 64 + sb * 32 + (r & 3) + 8 * (r >> 2) + 4 * hi;
                    if (dmask && s_g > qg_l) x2 = 0.f;
                    pv[r] = x2;
                }
                u32 W[8];
                #pragma unroll
                for (int t = 0; t < 8; ++t)
                    W[t] = bfu(pv[2 * t]) | (bfu(pv[2 * t + 1]) << 16);
                asm volatile("v_permlane32_swap_b32 %0, %1" : "+v"(W[0]), "+v"(W[2]));
                asm volatile("v_permlane32_swap_b32 %0, %1" : "+v"(W[1]), "+v"(W[3]));
                asm volatile("v_permlane32_swap_b32 %0, %1" : "+v"(W[4]), "+v"(W[6]));
                asm volatile("v_permlane32_swap_b32 %0, %1" : "+v"(W[5]), "+v"(W[7]));
                pa[sb * 2 + 0][0] = W[0]; pa[sb * 2 + 0][1] = W[1];
                pa[sb * 2 + 0][2] = W[2]; pa[sb * 2 + 0][3] = W[3];
                pa[sb * 2 + 1][0] = W[4]; pa[sb * 2 + 1][1] = W[5];
                pa[sb * 2 + 1][2] = W[6]; pa[sb * 2 + 1][3] = W[7];
            }

            // ---- PV ----
            const char* vb = kb + 8192;
            __builtin_amdgcn_s_setprio(1);
            #pragma unroll
            for (int dh = 0; dh < 2; ++dh)
                #pragma unroll
                for (int ks = 0; ks < 4; ++ks) {
                    bf16x8 vf = *(const bf16x8*)(vb + (dh * 4 + ks) * 1024 + lane * 16);
                    u32x4 pw = { pa[ks][0], pa[ks][1], pa[ks][2], pa[ks][3] };
                    oacc[dh] = MFMA32(__builtin_bit_cast(bf16x8, pw), vf, oacc[dh]);
                }
            __builtin_amdgcn_s_setprio(0);
        }
        __syncthreads();
    }

    // ---- ktp-pair reduction through LDS + fused u-gate epilogue ----
    float* red = (float*)&lds[0][0];             // [qs][m(32)][d(64)] f32 = 16KB
    if (ktp == 0) {
        #pragma unroll
        for (int dh = 0; dh < 2; ++dh)
            #pragma unroll
            for (int r = 0; r < 16; ++r) {
                const int m = (r & 3) + 8 * (r >> 2) + 4 * hi;
                red[(qs * 32 + m) * 64 + dh * 32 + col] = oacc[dh][r];
            }
    }
    __syncthreads();
    if (ktp == 1) {
        const float sc = 1.0f / (64.0f * 2048.0f);   // exact pow2
        #pragma unroll
        for (int dh = 0; dh < 2; ++dh)
            #pragma unroll
            for (int r = 0; r < 16; ++r) {
                const int m = (r & 3) + 8 * (r >> 2) + 4 * hi;
                const float o = oacc[dh][r] + red[(qs * 32 + m) * 64 + dh * 32 + col];
                const size_t idx = base + (size_t)(qw + m) * RS + dh * 32 + col;
                outg[idx] = ug[idx] * o * sc;
            }
    }
}

extern "C" void kernel_launch(void* const* d_in, const int* in_sizes, int n_in,
                              void* d_out, int out_size, void* d_ws, size_t ws_size,
                              hipStream_t stream) {
    const float* u = (const float*)d_in[0];
    const float* q = (const float*)d_in[1];
    const float* k = (const float*)d_in[2];
    const float* v = (const float*)d_in[3];
    // d_in[4] (mask) is strict-upper-triangular; implemented analytically.
    float* out = (float*)d_out;

    // ws: 16 bh x 32 kt x 16KB = 8 MiB fragment-ordered bf16 K/V tiles
    prep_kv<<<dim3(NKT, 16), dim3(256), 0, stream>>>(k, v, (short*)d_ws);
    gate_attn<<<dim3(512), dim3(256), 0, stream>>>(u, q, (const short*)d_ws, out);
}